// Round 1
// baseline (388.493 us; speedup 1.0000x reference)
//
#include <hip/hip_runtime.h>

#define N_NODES 1048576
#define N_SEG   16384
#define NPS     64
#define D       128
#define EPS     1e-5f

typedef float f4 __attribute__((ext_vector_type(4)));
typedef float f32x4 __attribute__((ext_vector_type(4)));
typedef __bf16 bf16x8 __attribute__((ext_vector_type(8)));

// ---------- K1: column sum / sumsq partials (deterministic, no atomics) ----------
// grid 2048 x 256. part layout: [256 stats*col][2048 blocks]
__global__ __launch_bounds__(256) void k_stats(const float* __restrict__ feat,
                                               float* __restrict__ part) {
    int t = threadIdx.x;
    long gid = (long)blockIdx.x * 256 + t;       // float4 index
    const f4* f4p = (const f4*)feat;
    f4 s = {0.f,0.f,0.f,0.f}, q = {0.f,0.f,0.f,0.f};
#pragma unroll 8
    for (int k = 0; k < 64; ++k) {
        f4 v = f4p[gid + (long)k * 524288];      // stride = 2048*256 float4s
        s += v;
        q += v * v;
    }
    __shared__ f4 red[2][8][32];
    red[0][t >> 5][t & 31] = s;
    red[1][t >> 5][t & 31] = q;
    __syncthreads();
    int stat = t >> 7, c = t & 127;
    const float* base = (const float*)&red[stat][0][0];
    float acc = 0.f;
#pragma unroll
    for (int r = 0; r < 8; ++r) acc += base[r * 128 + c];
    part[(stat * 128 + c) * 2048 + blockIdx.x] = acc;
}

// ---------- K1b: reduce partials -> scale/shift ----------
// grid 128 x 256; block c handles column c
__global__ __launch_bounds__(256) void k_scale(const float* __restrict__ part,
                                               const float* __restrict__ gamma,
                                               const float* __restrict__ beta,
                                               float* __restrict__ scl,
                                               float* __restrict__ shf) {
    int t = threadIdx.x, c = blockIdx.x;
    float s1 = 0.f, s2 = 0.f;
#pragma unroll
    for (int j = 0; j < 8; ++j) {
        s1 += part[c * 2048 + t + 256 * j];
        s2 += part[(128 + c) * 2048 + t + 256 * j];
    }
    __shared__ float rs[256], rq[256];
    rs[t] = s1; rq[t] = s2;
    __syncthreads();
    for (int off = 128; off > 0; off >>= 1) {
        if (t < off) { rs[t] += rs[t + off]; rq[t] += rq[t + off]; }
        __syncthreads();
    }
    if (t == 0) {
        float mean = rs[0] / (float)N_NODES;
        float var  = rq[0] / (float)N_NODES - mean * mean;
        float sc   = gamma[c] * rsqrtf(var + EPS);
        scl[c] = sc;
        shf[c] = beta[c] - mean * sc;
    }
}

// ---------- K_last: feat_last_pre[seg][h] = f[last]@W_i^T + b_i ----------
// grid 512 x 256; 32 segments per block. W_i^T in LDS, pad 129 (conflict-free).
__global__ __launch_bounds__(256) void k_last(const float* __restrict__ feat,
                                              const int* __restrict__ last_nodes,
                                              const float* __restrict__ Wi,
                                              const float* __restrict__ bi,
                                              const float* __restrict__ scl,
                                              const float* __restrict__ shf,
                                              float* __restrict__ flp) {
    __shared__ float sWiT[128][129];   // sWiT[d][h] = Wi[h][d]
    __shared__ float fl[128];
    __shared__ float comb[128];
    int t = threadIdx.x;
    for (int i = t; i < 16384; i += 256) sWiT[i & 127][i >> 7] = Wi[i];
    __syncthreads();
    for (int s = 0; s < 32; ++s) {
        int seg = blockIdx.x * 32 + s;
        int row = last_nodes[seg];
        if (t < 128) fl[t] = feat[(long)row * 128 + t] * scl[t] + shf[t];
        __syncthreads();
        int h = t & 127, half = t >> 7;
        float acc = 0.f;
#pragma unroll 8
        for (int d = 64 * half; d < 64 * half + 64; ++d) acc += fl[d] * sWiT[d][h];
        if (half) comb[h] = acc;
        __syncthreads();
        if (!half) flp[seg * 128 + h] = acc + comb[h] + bi[h];
        __syncthreads();
    }
}

// ---------- helpers ----------
__device__ inline unsigned pk2(float x, float y) {   // pack 2 floats -> 2 bf16 (RNE)
    unsigned a = __builtin_bit_cast(unsigned, x);
    unsigned b = __builtin_bit_cast(unsigned, y);
    a = (a + 0x7fffu + ((a >> 16) & 1u)) >> 16;
    b = (b + 0x7fffu + ((b >> 16) & 1u)) & 0xffff0000u;
    return a | b;
}
__device__ inline bf16x8 lds8(const unsigned short* p, int row, int kb) {
    int addr = (row * 256 + kb) ^ ((row & 7) << 4);  // T2 XOR swizzle
    return *(const bf16x8*)((const char*)p + addr);
}

// ---------- K2: fused normalize + GEMM(bf16 MFMA) + gate + segment softmax + sums ----
// grid 2048 x 256 (4 waves); 8 segments per block; 2 blocks/CU.
__global__ __launch_bounds__(256, 2) void k_main(const float* __restrict__ feat,
                                                 const float* __restrict__ pw,
                                                 const float* __restrict__ Wu,
                                                 const float* __restrict__ we,
                                                 const float* __restrict__ scl,
                                                 const float* __restrict__ shf,
                                                 const float* __restrict__ flp,
                                                 float* __restrict__ out) {
    __shared__ __align__(16) unsigned short sWu[128 * 128]; // bf16, swizzled, 32KB
    __shared__ __align__(16) unsigned short sA[64 * 128];   // bf16, swizzled, 16KB
    __shared__ float epart[4][64];
    __shared__ float alpha[64];
    __shared__ __align__(16) float partR[8][128];
    __shared__ __align__(16) float partP[8][128];

    int t = threadIdx.x;
    int lane = t & 63, w = t >> 6;
    int c0 = 4 * (t & 31);
    f4 vscl = *(const f4*)(scl + c0);
    f4 vshf = *(const f4*)(shf + c0);

    // stage Wu -> LDS bf16 swizzled
    const f4* Wu4 = (const f4*)Wu;
#pragma unroll
    for (int k = 0; k < 16; ++k) {
        int g = t + 256 * k;                 // float4 index, 4096 total
        f4 v = Wu4[g];
        int h = g >> 5;
        int addr = (h * 256 + (g & 31) * 8) ^ ((h & 7) << 4);
        *(uint2*)((char*)sWu + addr) = make_uint2(pk2(v.x, v.y), pk2(v.z, v.w));
    }
    int h_a = (lane & 15) + 32 * w;          // this lane's two h columns
    int h_b = h_a + 16;
    float we0 = we[h_a], we1 = we[h_b];
    __syncthreads();

    for (int it = 0; it < 8; ++it) {
        int seg = blockIdx.x * 8 + it;
        const f4* src = (const f4*)(feat + (long)seg * NPS * D);
        f4 f[8];
        float pwv[8];
#pragma unroll
        for (int k = 0; k < 8; ++k) {
            f4 v = src[t + 256 * k];         // node (t>>5)+8k, cols c0..c0+3
            f[k] = v * vscl + vshf;          // normalized f32 kept in registers
        }
#pragma unroll
        for (int k = 0; k < 8; ++k) pwv[k] = pw[seg * NPS + (t >> 5) + 8 * k];
        float fl0 = flp[seg * 128 + h_a];
        float fl1 = flp[seg * 128 + h_b];
        // write bf16 tile (swizzled)
#pragma unroll
        for (int k = 0; k < 8; ++k) {
            int n = (t >> 5) + 8 * k;
            int addr = (n * 256 + 8 * (t & 31)) ^ ((n & 7) << 4);
            *(uint2*)((char*)sA + addr) = make_uint2(pk2(f[k].x, f[k].y), pk2(f[k].z, f[k].w));
        }
        __syncthreads();

        // U[n][h] = f @ Wu^T ; wave w owns h in [32w, 32w+32)
        f32x4 acc[4][2];
#pragma unroll
        for (int nf = 0; nf < 4; ++nf)
#pragma unroll
            for (int hf = 0; hf < 2; ++hf) acc[nf][hf] = (f32x4){0.f,0.f,0.f,0.f};
        int lo = lane & 15, g4 = lane >> 4;
#pragma unroll
        for (int kk = 0; kk < 4; ++kk) {
            int kb = kk * 64 + g4 * 16;      // byte offset of this lane's k-chunk
            bf16x8 b0 = lds8(sWu, h_a, kb);
            bf16x8 b1 = lds8(sWu, h_b, kb);
            bf16x8 a[4];
#pragma unroll
            for (int nf = 0; nf < 4; ++nf) a[nf] = lds8(sA, lo + 16 * nf, kb);
#pragma unroll
            for (int nf = 0; nf < 4; ++nf) {
                acc[nf][0] = __builtin_amdgcn_mfma_f32_16x16x32_bf16(a[nf], b0, acc[nf][0], 0, 0, 0);
                acc[nf][1] = __builtin_amdgcn_mfma_f32_16x16x32_bf16(a[nf], b1, acc[nf][1], 0, 0, 0);
            }
        }

        // e[n] partials: sigmoid(U + feat_last) . w_e, reduced over 16-lane groups
#pragma unroll
        for (int nf = 0; nf < 4; ++nf) {
#pragma unroll
            for (int r = 0; r < 4; ++r) {
                float x0 = acc[nf][0][r] + fl0;
                float x1 = acc[nf][1][r] + fl1;
                float p = we0 / (1.f + __expf(-x0)) + we1 / (1.f + __expf(-x1));
                p += __shfl_xor(p, 1);
                p += __shfl_xor(p, 2);
                p += __shfl_xor(p, 4);
                p += __shfl_xor(p, 8);
                if ((lane & 15) == 0) epart[w][16 * nf + 4 * g4 + r] = p;
            }
        }
        __syncthreads();

        // segment softmax over 64 nodes (wave 0)
        if (t < 64) {
            float e = epart[0][t] + epart[1][t] + epart[2][t] + epart[3][t];
            float m = e;
#pragma unroll
            for (int off = 32; off > 0; off >>= 1) m = fmaxf(m, __shfl_xor(m, off));
            float ex = __expf(e - m);
            float sd = ex;
#pragma unroll
            for (int off = 32; off > 0; off >>= 1) sd += __shfl_xor(sd, off);
            alpha[t] = ex / sd;
        }
        __syncthreads();

        // weighted sums from f32 registers
        f4 racc = {0.f,0.f,0.f,0.f}, pacc = {0.f,0.f,0.f,0.f};
#pragma unroll
        for (int k = 0; k < 8; ++k) {
            float av = alpha[(t >> 5) + 8 * k];
            racc += av * f[k];
            pacc += pwv[k] * f[k];
        }
        *(f4*)&partR[t >> 5][c0] = racc;
        *(f4*)&partP[t >> 5][c0] = pacc;
        __syncthreads();

        if (t < 128) {
            float s = 0.f;
#pragma unroll
            for (int r = 0; r < 8; ++r) s += partR[r][t];
            out[(long)seg * 128 + t] = s;
        } else {
            int c = t - 128;
            float s = 0.f;
#pragma unroll
            for (int r = 0; r < 8; ++r) s += partP[r][c];
            out[(long)N_SEG * 128 + (long)seg * 128 + c] = s;
        }
        __syncthreads();
    }
}

extern "C" void kernel_launch(void* const* d_in, const int* in_sizes, int n_in,
                              void* d_out, int out_size, void* d_ws, size_t ws_size,
                              hipStream_t stream) {
    const float* feat       = (const float*)d_in[0];
    const float* pw         = (const float*)d_in[1];
    const int*   last_nodes = (const int*)d_in[2];
    // d_in[3] segment_ids: contiguous equal segments (seg = node>>6) -- implicit
    const float* gamma      = (const float*)d_in[4];
    const float* beta       = (const float*)d_in[5];
    const float* Wu         = (const float*)d_in[6];
    const float* Wi         = (const float*)d_in[7];
    const float* bi         = (const float*)d_in[8];
    const float* we         = (const float*)d_in[9];
    float* out = (float*)d_out;

    float* ws   = (float*)d_ws;
    float* part = ws;                       // 256*2048 floats (2 MB)
    float* wscl = ws + 524288;              // 128
    float* wshf = ws + 524288 + 128;        // 128
    float* flp  = ws + 524288 + 256;        // 16384*128 floats (8 MB)

    k_stats<<<dim3(2048), dim3(256), 0, stream>>>(feat, part);
    k_scale<<<dim3(128),  dim3(256), 0, stream>>>(part, gamma, beta, wscl, wshf);
    k_last <<<dim3(512),  dim3(256), 0, stream>>>(feat, last_nodes, Wi, bi, wscl, wshf, flp);
    k_main <<<dim3(2048), dim3(256), 0, stream>>>(feat, pw, Wu, we, wscl, wshf, flp, out);
}